// Round 1
// baseline (1417.827 us; speedup 1.0000x reference)
//
#include <hip/hip_runtime.h>
#include <math.h>

#define NN 8192
#define WSZ 64
#define RH 4
#define BB 32
#define HD 256
#define INSZ 512
#define ISZ 468

// ---- workspace float offsets ----
#define OFF_IFACE   0            // 32*468 = 14976
#define OFF_ALLOC   14976        // 8192
#define OFF_RCW     23168        // 128*8192
#define OFF_WCW     1071744      // 32*8192
#define OFF_WW      1333888      // 32*8192
#define OFF_WV      1596032      // 8192
#define OFF_RCWT    1604224      // 8192*128
#define OFF_FWD     2652800      // 128*8192
#define OFF_BWD     3701376      // 128*8192
#define OFF_RW      4749952      // 128*8192
#define OFF_SCAL    5798528      // [0]=wsum, [1]=fg_mean
#define OFF_E       5798592      // 64
#define OFF_V       5798656     // 64  (end 5798720 floats = 23.2 MB)

// ---- output float offsets (flat concat of return tuple) ----
#define OUT_RV      0
#define OUT_H       8192
#define OUT_MEM     16384
#define OUT_USAGE   540672
#define OUT_LINK    548864
#define OUT_PREC    67657728

__device__ __forceinline__ float sigm(float x){ return 1.0f/(1.0f+expf(-x)); }
__device__ __forceinline__ float softplusf_(float x){ return fmaxf(x,0.0f) + log1pf(expf(-fabsf(x))); }

// ---------------- K1: LSTM controller + interface projection ----------------
__global__ __launch_bounds__(256) void k_controller(
    const float* __restrict__ input_data, const float* __restrict__ prev_reads,
    const float* __restrict__ h0, const float* __restrict__ c0,
    const float* __restrict__ W_ih, const float* __restrict__ W_hh,
    const float* __restrict__ b_ih, const float* __restrict__ b_hh,
    const float* __restrict__ W_if, const float* __restrict__ b_if,
    float* __restrict__ out, float* __restrict__ ws)
{
  int b = blockIdx.x, t = threadIdx.x;
  __shared__ float xs[1024];
  for (int i = t; i < 768; i += 256)
    xs[i] = (i < 512) ? input_data[b*INSZ + i] : prev_reads[b*256 + (i-512)];
  xs[768 + t] = h0[b*HD + t];
  __syncthreads();
  float g[4];
  #pragma unroll
  for (int gi = 0; gi < 4; gi++){
    int row = gi*256 + t;
    float acc = b_ih[row] + b_hh[row];
    const float4* wr = (const float4*)(W_ih + (size_t)row*768);
    #pragma unroll 8
    for (int k = 0; k < 192; k++){
      float4 w4 = wr[k];
      const float* xp = &xs[k*4];
      acc += w4.x*xp[0] + w4.y*xp[1] + w4.z*xp[2] + w4.w*xp[3];
    }
    const float4* hr = (const float4*)(W_hh + (size_t)row*256);
    #pragma unroll 8
    for (int k = 0; k < 64; k++){
      float4 w4 = hr[k];
      const float* xp = &xs[768 + k*4];
      acc += w4.x*xp[0] + w4.y*xp[1] + w4.z*xp[2] + w4.w*xp[3];
    }
    g[gi] = acc;
  }
  float c = sigm(g[1])*c0[b*HD+t] + sigm(g[0])*tanhf(g[2]);
  float h = sigm(g[3])*tanhf(c);
  out[OUT_H + b*HD + t] = h;
  __syncthreads();
  xs[t] = h;
  __syncthreads();
  float* ifb = ws + OFF_IFACE + b*ISZ;
  for (int o = t; o < ISZ; o += 256){
    float acc = b_if[o];
    const float4* wr = (const float4*)(W_if + (size_t)o*256);
    #pragma unroll 8
    for (int k = 0; k < 64; k++){
      float4 w4 = wr[k];
      const float* xp = &xs[k*4];
      acc += w4.x*xp[0] + w4.y*xp[1] + w4.z*xp[2] + w4.w*xp[3];
    }
    ifb[o] = acc;
  }
}

// ---------------- K2: allocation weighting (10 least-used slots) ----------------
__global__ __launch_bounds__(1024) void k_alloc(const float* __restrict__ usage, float* __restrict__ ws)
{
  int t = threadIdx.x;
  float* allocv = ws + OFF_ALLOC;
  for (int i = t; i < NN; i += 1024) allocv[i] = 0.0f;
  float v[8]; int id[8];
  #pragma unroll
  for (int i = 0; i < 8; i++){ int n = i*1024 + t; v[i] = usage[n]; id[i] = n; }
  __shared__ float rv_[1024]; __shared__ int ri_[1024];
  __syncthreads();
  for (int k = 0; k < 10; k++){
    float bv = INFINITY; int bi = NN;
    #pragma unroll
    for (int i = 0; i < 8; i++){
      if (v[i] < bv || (v[i] == bv && id[i] < bi)){ bv = v[i]; bi = id[i]; }
    }
    rv_[t] = bv; ri_[t] = bi;
    __syncthreads();
    for (int s = 512; s > 0; s >>= 1){
      if (t < s){
        if (rv_[t+s] < rv_[t] || (rv_[t+s] == rv_[t] && ri_[t+s] < ri_[t])){
          rv_[t] = rv_[t+s]; ri_[t] = ri_[t+s];
        }
      }
      __syncthreads();
    }
    int sel = ri_[0];
    __syncthreads();
    #pragma unroll
    for (int i = 0; i < 8; i++) if (id[i] == sel) v[i] = INFINITY;
    if (t == 0) allocv[sel] = (float)(((double)(10-k)/10.0) / (5.5 + 1e-8));
  }
}

// ---------------- K3: content addressing (cosine sim + sharpened softmax) ----------------
__global__ __launch_bounds__(256) void k_content(
    const float* __restrict__ memory, float* __restrict__ ws)
{
  int b = blockIdx.x, hh = blockIdx.y, t = threadIdx.x;
  __shared__ float keyn[64];
  __shared__ float red[256];
  const float* ifb = ws + OFF_IFACE + b*ISZ;
  int koff = (hh < 4) ? hh*64 : 260;
  float kv = (t < 64) ? ifb[koff + t] : 0.0f;
  red[t] = kv*kv;
  __syncthreads();
  for (int s = 128; s > 0; s >>= 1){ if (t < s) red[t] += red[t+s]; __syncthreads(); }
  float inv = 1.0f / fmaxf(sqrtf(red[0]), 1e-12f);
  __syncthreads();
  if (t < 64) keyn[t] = kv * inv;
  float strength = softplusf_(ifb[(hh<4) ? (256+hh) : 324]) + 1.0f;
  __syncthreads();
  float s_[32];
  float lmax = -INFINITY;
  for (int i = 0; i < 32; i++){
    int n = i*256 + t;
    const float4* row = (const float4*)(memory + (size_t)n*64);
    float dot = 0.0f, nsq = 0.0f;
    #pragma unroll
    for (int j = 0; j < 16; j++){
      float4 m4 = row[j];
      const float* kp = &keyn[j*4];
      dot += m4.x*kp[0] + m4.y*kp[1] + m4.z*kp[2] + m4.w*kp[3];
      nsq += m4.x*m4.x + m4.y*m4.y + m4.z*m4.z + m4.w*m4.w;
    }
    float sim = dot / fmaxf(sqrtf(nsq), 1e-12f);
    s_[i] = sim * strength;
    lmax = fmaxf(lmax, s_[i]);
  }
  red[t] = lmax; __syncthreads();
  for (int s = 128; s > 0; s >>= 1){ if (t < s) red[t] = fmaxf(red[t], red[t+s]); __syncthreads(); }
  float M = red[0]; __syncthreads();
  float lsum = 0.0f;
  for (int i = 0; i < 32; i++) lsum += expf(s_[i] - M);
  red[t] = lsum; __syncthreads();
  for (int s = 128; s > 0; s >>= 1){ if (t < s) red[t] += red[t+s]; __syncthreads(); }
  float invS = 1.0f / red[0];
  if (hh < 4){
    float* dst = ws + OFF_RCW + (size_t)(b*4 + hh)*NN;
    for (int i = 0; i < 32; i++) dst[i*256 + t] = expf(s_[i] - M) * invS;
  } else {
    float* dstw = ws + OFF_WCW + (size_t)b*NN;
    float* dstww = ws + OFF_WW + (size_t)b*NN;
    const float* allocv = ws + OFF_ALLOC;
    float ag = sigm(ifb[454]);
    float wg = sigm(ifb[455]);
    for (int i = 0; i < 32; i++){
      int n = i*256 + t;
      float p = expf(s_[i] - M) * invS;
      dstw[n] = p;
      dstww[n] = wg * (ag * allocv[n] + (1.0f - ag) * p);
    }
  }
}

// ---------------- K4: batch-mean write weight w[n], wsum, fg_mean, e[], v[] ----------------
__global__ __launch_bounds__(256) void k_wmean(float* __restrict__ ws)
{
  int t = threadIdx.x, n = blockIdx.x*256 + t;
  const float* ww = ws + OFF_WW;
  float s = 0.0f;
  #pragma unroll 8
  for (int b = 0; b < 32; b++) s += ww[(size_t)b*NN + n];
  float w_n = s * (1.0f/32.0f);
  ws[OFF_WV + n] = w_n;
  __shared__ float red[256];
  red[t] = w_n; __syncthreads();
  for (int s2 = 128; s2 > 0; s2 >>= 1){ if (t < s2) red[t] += red[t+s2]; __syncthreads(); }
  if (t == 0) atomicAdd(ws + OFF_SCAL, red[0]);
  if (blockIdx.x == 0){
    __syncthreads();
    const float* iface = ws + OFF_IFACE;
    red[t] = (t < 32) ? sigm(iface[t*ISZ + 453]) : 0.0f;
    __syncthreads();
    for (int s2 = 128; s2 > 0; s2 >>= 1){ if (t < s2) red[t] += red[t+s2]; __syncthreads(); }
    if (t == 0) ws[OFF_SCAL + 1] = red[0] * (1.0f/32.0f);
    if (t < 64){
      float se = 0.0f, sv = 0.0f;
      for (int b = 0; b < 32; b++){
        se += sigm(iface[b*ISZ + 389 + t]);
        sv += iface[b*ISZ + 325 + t];
      }
      ws[OFF_E + t] = se * (1.0f/32.0f);
      ws[OFF_V + t] = sv * (1.0f/32.0f);
    }
  }
}

// ---------------- K4b: transpose rcw [128][8192] -> rcwT [8192][128] ----------------
__global__ __launch_bounds__(256) void k_transpose(float* __restrict__ ws)
{
  __shared__ float tl[32][33];
  int t = threadIdx.x;
  int n0 = blockIdx.x * 32, bh0 = blockIdx.y * 32;
  int r = t >> 3, c4 = (t & 7) * 4;
  const float* rcw = ws + OFF_RCW;
  float4 L = *(const float4*)(rcw + (size_t)(bh0 + r)*NN + n0 + c4);
  tl[r][c4+0] = L.x; tl[r][c4+1] = L.y; tl[r][c4+2] = L.z; tl[r][c4+3] = L.w;
  __syncthreads();
  float* rcwT = ws + OFF_RCWT;
  float4 o;
  o.x = tl[c4+0][r]; o.y = tl[c4+1][r]; o.z = tl[c4+2][r]; o.w = tl[c4+3][r];
  *(float4*)(rcwT + (size_t)(n0 + r)*128 + bh0 + c4) = o;
}

// ---------------- K5: link GEMMs. FWD=false: bwd + fused new_link. FWD=true: fwd ----------------
template<bool FWD>
__global__ __launch_bounds__(256) void k_link_gemm(
    const float* __restrict__ link, const float* __restrict__ prec,
    float* __restrict__ ws, float* __restrict__ new_link)
{
  __shared__ float Al[32][128];
  __shared__ float Bl[32][36];
  const float* rcwT = ws + OFF_RCWT;
  const float* wv = ws + OFF_WV;
  float* outAcc = ws + (FWD ? OFF_FWD : OFF_BWD);
  int t = threadIdx.x;
  int p0 = blockIdx.x * 32;             // output n (bwd) / m (fwd) stripe
  int kbeg = blockIdx.y * 4096, kend = kbeg + 4096;
  int bhg = t & 31, ng = t >> 5;
  int r = t >> 3, c4 = (t & 7) * 4;
  float acc[4][4] = {};
  for (int kt = kbeg; kt < kend; kt += 32){
    const float4* asrc = (const float4*)(rcwT + (size_t)kt*128);
    float4* adst = (float4*)(&Al[0][0]);
    #pragma unroll
    for (int i = 0; i < 4; i++) adst[t + i*256] = asrc[t + i*256];
    if (!FWD){
      int n = p0 + r;                   // link row = output row stripe, K = columns m
      float4 L = *(const float4*)(link + (size_t)n*NN + kt + c4);
      float w_n = wv[n];
      float4 nl;
      float* lp = (float*)&L; float* np = (float*)&nl;
      #pragma unroll
      for (int i = 0; i < 4; i++){
        int m = kt + c4 + i;
        float li = lp[i];
        float vv = (1.0f - w_n - wv[m]) * li + w_n * prec[m];
        np[i] = (n == m) ? 0.0f : vv;
        Bl[c4+i][r] = li;               // Bl[k=m][n]
      }
      *(float4*)(new_link + (size_t)n*NN + kt + c4) = nl;
    } else {
      int n = kt + r;                   // link row = K, columns = output m stripe
      float4 L = *(const float4*)(link + (size_t)n*NN + p0 + c4);
      *(float4*)(&Bl[r][c4]) = L;       // Bl[k=n][m]
    }
    __syncthreads();
    #pragma unroll
    for (int k = 0; k < 32; k++){
      float4 a  = *(const float4*)(&Al[k][bhg*4]);
      float4 bq = *(const float4*)(&Bl[k][ng*4]);
      acc[0][0] += a.x*bq.x; acc[0][1] += a.x*bq.y; acc[0][2] += a.x*bq.z; acc[0][3] += a.x*bq.w;
      acc[1][0] += a.y*bq.x; acc[1][1] += a.y*bq.y; acc[1][2] += a.y*bq.z; acc[1][3] += a.y*bq.w;
      acc[2][0] += a.z*bq.x; acc[2][1] += a.z*bq.y; acc[2][2] += a.z*bq.z; acc[2][3] += a.z*bq.w;
      acc[3][0] += a.w*bq.x; acc[3][1] += a.w*bq.y; acc[3][2] += a.w*bq.z; acc[3][3] += a.w*bq.w;
    }
    __syncthreads();
  }
  #pragma unroll
  for (int i = 0; i < 4; i++){
    #pragma unroll
    for (int j = 0; j < 4; j++){
      atomicAdd(&outAcc[(size_t)(bhg*4 + i)*NN + p0 + ng*4 + j], acc[i][j]);
    }
  }
}

// ---------------- K6: read weights (mode mix) ----------------
__global__ __launch_bounds__(256) void k_read_weights(float* __restrict__ ws)
{
  int bh = blockIdx.x, t = threadIdx.x;
  int b = bh >> 2, rr = bh & 3;
  const float* ifb = ws + OFF_IFACE + b*ISZ + 456 + rr*3;
  float m0 = ifb[0], m1 = ifb[1], m2 = ifb[2];
  float mx = fmaxf(m0, fmaxf(m1, m2));
  float e0 = expf(m0-mx), e1 = expf(m1-mx), e2 = expf(m2-mx);
  float inv = 1.0f/(e0+e1+e2);
  m0 = e0*inv; m1 = e1*inv; m2 = e2*inv;
  const float* fwd = ws + OFF_FWD + (size_t)bh*NN;
  const float* bwd = ws + OFF_BWD + (size_t)bh*NN;
  const float* rcw = ws + OFF_RCW + (size_t)bh*NN;
  float* rw = ws + OFF_RW + (size_t)bh*NN;
  for (int n = t; n < NN; n += 256)
    rw[n] = m0*bwd[n] + m1*rcw[n] + m2*fwd[n];
}

// ---------------- K6b: read vectors ----------------
__global__ __launch_bounds__(256) void k_read_vectors(
    const float* __restrict__ memory, const float* __restrict__ ws_c, float* __restrict__ out)
{
  int bh = blockIdx.x, t = threadIdx.x;
  int w = t >> 6, j = t & 63;
  const float* rw = ws_c + OFF_RW + (size_t)bh*NN;
  float a0=0, a1=0, a2=0, a3=0;
  int nbase = w*2048;
  for (int i = 0; i < 2048; i += 4){
    int n = nbase + i;
    a0 += rw[n+0]*memory[(size_t)(n+0)*64 + j];
    a1 += rw[n+1]*memory[(size_t)(n+1)*64 + j];
    a2 += rw[n+2]*memory[(size_t)(n+2)*64 + j];
    a3 += rw[n+3]*memory[(size_t)(n+3)*64 + j];
  }
  __shared__ float red[4][64];
  red[w][j] = ((a0+a1)+(a2+a3));
  __syncthreads();
  if (t < 64){
    float s = red[0][t] + red[1][t] + red[2][t] + red[3][t];
    out[OUT_RV + (bh>>2)*256 + (bh&3)*64 + t] = s;
  }
}

// ---------------- K7: usage + precedence ----------------
__global__ __launch_bounds__(256) void k_usage_prec(
    const float* __restrict__ usage, const float* __restrict__ prec,
    const float* __restrict__ ws_c, float* __restrict__ out)
{
  int n = blockIdx.x*256 + threadIdx.x;
  const float* rw = ws_c + OFF_RW;
  float s = 0.0f;
  #pragma unroll 8
  for (int bh = 0; bh < 128; bh++) s += rw[(size_t)bh*NN + n];
  float fg = ws_c[OFF_SCAL + 1];
  float retention = 1.0f - fg * (s * (1.0f/128.0f));
  float u = usage[n], w_n = ws_c[OFF_WV + n];
  out[OUT_USAGE + n] = (u + w_n - u*w_n) * retention;
  float wsum = ws_c[OFF_SCAL];
  out[OUT_PREC + n] = (1.0f - wsum) * prec[n] + w_n;
}

// ---------------- K8: memory update ----------------
__global__ __launch_bounds__(256) void k_new_memory(
    const float* __restrict__ memory, const float* __restrict__ ws_c, float* __restrict__ out)
{
  int idx = blockIdx.x*256 + threadIdx.x;
  int n = idx >> 6, j = idx & 63;
  float w_n = ws_c[OFF_WV + n];
  out[OUT_MEM + idx] = memory[idx] * (1.0f - w_n * ws_c[OFF_E + j]) + w_n * ws_c[OFF_V + j];
}

extern "C" void kernel_launch(void* const* d_in, const int* in_sizes, int n_in,
                              void* d_out, int out_size, void* d_ws, size_t ws_size,
                              hipStream_t stream)
{
  const float* input_data = (const float*)d_in[0];
  const float* prev_reads = (const float*)d_in[1];
  const float* h0         = (const float*)d_in[2];
  const float* c0         = (const float*)d_in[3];
  const float* memory     = (const float*)d_in[4];
  const float* usage      = (const float*)d_in[5];
  const float* link       = (const float*)d_in[6];
  const float* prec       = (const float*)d_in[7];
  const float* W_ih       = (const float*)d_in[8];
  const float* W_hh       = (const float*)d_in[9];
  const float* b_ih       = (const float*)d_in[10];
  const float* b_hh       = (const float*)d_in[11];
  const float* W_if       = (const float*)d_in[12];
  const float* b_if       = (const float*)d_in[13];
  float* out = (float*)d_out;
  float* ws  = (float*)d_ws;

  // zero fwd+bwd accumulators (contiguous) and scalars
  hipMemsetAsync(ws + OFF_FWD, 0, (size_t)2*128*NN*sizeof(float), stream);
  hipMemsetAsync(ws + OFF_SCAL, 0, 2*sizeof(float), stream);

  k_controller<<<32, 256, 0, stream>>>(input_data, prev_reads, h0, c0,
                                       W_ih, W_hh, b_ih, b_hh, W_if, b_if, out, ws);
  k_alloc<<<1, 1024, 0, stream>>>(usage, ws);
  k_content<<<dim3(32,5), 256, 0, stream>>>(memory, ws);
  k_wmean<<<32, 256, 0, stream>>>(ws);
  k_transpose<<<dim3(256,4), 256, 0, stream>>>(ws);
  k_link_gemm<false><<<dim3(256,2), 256, 0, stream>>>(link, prec, ws, out + OUT_LINK);
  k_link_gemm<true ><<<dim3(256,2), 256, 0, stream>>>(link, prec, ws, out + OUT_LINK);
  k_read_weights<<<128, 256, 0, stream>>>(ws);
  k_read_vectors<<<128, 256, 0, stream>>>(memory, ws, out);
  k_usage_prec<<<32, 256, 0, stream>>>(usage, prec, ws, out);
  k_new_memory<<<2048, 256, 0, stream>>>(memory, ws, out);
}

// Round 3
// 1114.566 us; speedup vs baseline: 1.2721x; 1.2721x over previous
//
#include <hip/hip_runtime.h>
#include <math.h>

#define NN 8192
#define WSZ 64
#define RH 4
#define BB 32
#define HD 256
#define INSZ 512
#define ISZ 468

// ---- workspace float offsets ----
#define OFF_IFACE   0            // 32*468 = 14976
#define OFF_ALLOC   14976        // 8192 -> 23168
#define OFF_WW      23168        // 32*8192 = 262144 -> 285312
#define OFF_WV      285312       // 8192 -> 293504
#define OFF_MODE    293504       // 2*128 (m0 for bwd, m2 for fwd) -> 293760
#define OFF_SCAL    293760       // [0]=wsum [1]=fg_mean
#define OFF_E       293824       // 64
#define OFF_V       293888       // 64 -> 293952
#define OFF_RW      294912       // 128*8192 = 1048576 -> 1343488  (16B aligned)
#define OFF_RCWB    1343488      // 128*8192 bf16 = 524288 floats -> 1867776 (~7.5MB total)

// ---- output float offsets ----
#define OUT_RV      0
#define OUT_H       8192
#define OUT_MEM     16384
#define OUT_USAGE   540672
#define OUT_LINK    548864
#define OUT_PREC    67657728

typedef __bf16 bf16x8 __attribute__((ext_vector_type(8)));
typedef float  f32x16 __attribute__((ext_vector_type(16)));

__device__ __forceinline__ float sigm(float x){ return 1.0f/(1.0f+expf(-x)); }
__device__ __forceinline__ float softplusf_(float x){ return fmaxf(x,0.0f) + log1pf(expf(-fabsf(x))); }

// ---------------- K1: LSTM controller + interface projection (+ zero rv) ----------------
__global__ __launch_bounds__(256) void k_controller(
    const float* __restrict__ input_data, const float* __restrict__ prev_reads,
    const float* __restrict__ h0, const float* __restrict__ c0,
    const float* __restrict__ W_ih, const float* __restrict__ W_hh,
    const float* __restrict__ b_ih, const float* __restrict__ b_hh,
    const float* __restrict__ W_if, const float* __restrict__ b_if,
    float* __restrict__ out, float* __restrict__ ws)
{
  int b = blockIdx.x, t = threadIdx.x;
  out[OUT_RV + b*256 + t] = 0.0f;   // zero read_vectors accumulator region
  __shared__ float xs[1024];
  for (int i = t; i < 768; i += 256)
    xs[i] = (i < 512) ? input_data[b*INSZ + i] : prev_reads[b*256 + (i-512)];
  xs[768 + t] = h0[b*HD + t];
  __syncthreads();
  float g[4];
  #pragma unroll
  for (int gi = 0; gi < 4; gi++){
    int row = gi*256 + t;
    float acc = b_ih[row] + b_hh[row];
    const float4* wr = (const float4*)(W_ih + (size_t)row*768);
    #pragma unroll 8
    for (int k = 0; k < 192; k++){
      float4 w4 = wr[k];
      const float* xp = &xs[k*4];
      acc += w4.x*xp[0] + w4.y*xp[1] + w4.z*xp[2] + w4.w*xp[3];
    }
    const float4* hr = (const float4*)(W_hh + (size_t)row*256);
    #pragma unroll 8
    for (int k = 0; k < 64; k++){
      float4 w4 = hr[k];
      const float* xp = &xs[768 + k*4];
      acc += w4.x*xp[0] + w4.y*xp[1] + w4.z*xp[2] + w4.w*xp[3];
    }
    g[gi] = acc;
  }
  float c = sigm(g[1])*c0[b*HD+t] + sigm(g[0])*tanhf(g[2]);
  float h = sigm(g[3])*tanhf(c);
  out[OUT_H + b*HD + t] = h;
  __syncthreads();
  xs[t] = h;
  __syncthreads();
  float* ifb = ws + OFF_IFACE + b*ISZ;
  for (int o = t; o < ISZ; o += 256){
    float acc = b_if[o];
    const float4* wr = (const float4*)(W_if + (size_t)o*256);
    #pragma unroll 8
    for (int k = 0; k < 64; k++){
      float4 w4 = wr[k];
      const float* xp = &xs[k*4];
      acc += w4.x*xp[0] + w4.y*xp[1] + w4.z*xp[2] + w4.w*xp[3];
    }
    ifb[o] = acc;
  }
}

// ---------------- K2: allocation weighting (10 least-used slots), shfl-based ----------------
__global__ __launch_bounds__(1024) void k_alloc(const float* __restrict__ usage, float* __restrict__ ws)
{
  int t = threadIdx.x, lane = t & 63, wid = t >> 6;   // 16 waves
  float* allocv = ws + OFF_ALLOC;
  for (int i = t; i < NN; i += 1024) allocv[i] = 0.0f;
  float v[8];
  #pragma unroll
  for (int i = 0; i < 8; i++) v[i] = usage[i*1024 + t];
  __shared__ float sv[16]; __shared__ int si[16]; __shared__ int ssel;
  __syncthreads();
  for (int k = 0; k < 10; k++){
    float bv = INFINITY; int bi = 0x7fffffff;
    #pragma unroll
    for (int i = 0; i < 8; i++){
      int n = i*1024 + t;
      if (v[i] < bv || (v[i] == bv && n < bi)){ bv = v[i]; bi = n; }
    }
    #pragma unroll
    for (int s = 32; s > 0; s >>= 1){
      float ov = __shfl_xor(bv, s);
      int   oi = __shfl_xor(bi, s);
      if (ov < bv || (ov == bv && oi < bi)){ bv = ov; bi = oi; }
    }
    if (lane == 0){ sv[wid] = bv; si[wid] = bi; }
    __syncthreads();
    if (wid == 0){
      float mv = (lane < 16) ? sv[lane] : INFINITY;
      int   mi = (lane < 16) ? si[lane] : 0x7fffffff;
      #pragma unroll
      for (int s = 8; s > 0; s >>= 1){
        float ov = __shfl_xor(mv, s);
        int   oi = __shfl_xor(mi, s);
        if (ov < mv || (ov == mv && oi < mi)){ mv = ov; mi = oi; }
      }
      if (lane == 0){
        ssel = mi;
        allocv[mi] = (float)(((double)(10-k)/10.0) / (5.5 + 1e-8));
      }
    }
    __syncthreads();
    int sel = ssel;
    if ((sel & 1023) == t) v[sel >> 10] = INFINITY;
  }
}

// ---------------- K3: content addressing; seeds rw = m1*rcw, writes bf16 rcw, modes ----------------
__global__ __launch_bounds__(256) void k_content(
    const float* __restrict__ memory, float* __restrict__ ws)
{
  int b = blockIdx.x, hh = blockIdx.y, t = threadIdx.x;
  __shared__ float keyn[64];
  __shared__ float red[256];
  const float* ifb = ws + OFF_IFACE + b*ISZ;
  int koff = (hh < 4) ? hh*64 : 260;
  float kv = (t < 64) ? ifb[koff + t] : 0.0f;
  red[t] = kv*kv;
  __syncthreads();
  for (int s = 128; s > 0; s >>= 1){ if (t < s) red[t] += red[t+s]; __syncthreads(); }
  float inv = 1.0f / fmaxf(sqrtf(red[0]), 1e-12f);
  __syncthreads();
  if (t < 64) keyn[t] = kv * inv;
  float strength = softplusf_(ifb[(hh<4) ? (256+hh) : 324]) + 1.0f;
  __syncthreads();
  float s_[32];
  float lmax = -INFINITY;
  for (int i = 0; i < 32; i++){
    int n = i*256 + t;
    const float4* row = (const float4*)(memory + (size_t)n*64);
    float dot = 0.0f, nsq = 0.0f;
    #pragma unroll
    for (int j = 0; j < 16; j++){
      float4 m4 = row[j];
      const float* kp = &keyn[j*4];
      dot += m4.x*kp[0] + m4.y*kp[1] + m4.z*kp[2] + m4.w*kp[3];
      nsq += m4.x*m4.x + m4.y*m4.y + m4.z*m4.z + m4.w*m4.w;
    }
    float sim = dot / fmaxf(sqrtf(nsq), 1e-12f);
    s_[i] = sim * strength;
    lmax = fmaxf(lmax, s_[i]);
  }
  red[t] = lmax; __syncthreads();
  for (int s = 128; s > 0; s >>= 1){ if (t < s) red[t] = fmaxf(red[t], red[t+s]); __syncthreads(); }
  float M = red[0]; __syncthreads();
  float p_[32];
  float lsum = 0.0f;
  #pragma unroll
  for (int i = 0; i < 32; i++){ p_[i] = expf(s_[i] - M); lsum += p_[i]; }
  red[t] = lsum; __syncthreads();
  for (int s = 128; s > 0; s >>= 1){ if (t < s) red[t] += red[t+s]; __syncthreads(); }
  float invS = 1.0f / red[0];
  if (hh < 4){
    int bh = b*4 + hh;
    // read modes softmax for this (b, r)
    float mr0 = ifb[456 + hh*3 + 0], mr1 = ifb[456 + hh*3 + 1], mr2 = ifb[456 + hh*3 + 2];
    float mx = fmaxf(mr0, fmaxf(mr1, mr2));
    float e0 = expf(mr0-mx), e1 = expf(mr1-mx), e2 = expf(mr2-mx);
    float einv = 1.0f/(e0+e1+e2);
    float m0 = e0*einv, m1 = e1*einv, m2 = e2*einv;
    if (t == 0){ ws[OFF_MODE + bh] = m0; ws[OFF_MODE + 128 + bh] = m2; }
    float* rw = ws + OFF_RW + (size_t)bh*NN;
    __bf16* rb = (__bf16*)(ws + OFF_RCWB) + (size_t)bh*NN;
    for (int i = 0; i < 32; i++){
      int n = i*256 + t;
      float p = p_[i] * invS;
      rw[n] = m1 * p;            // seed read_weights with content term
      rb[n] = (__bf16)p;         // bf16 A-operand for MFMA
    }
  } else {
    float* dstww = ws + OFF_WW + (size_t)b*NN;
    const float* allocv = ws + OFF_ALLOC;
    float ag = sigm(ifb[454]);
    float wg = sigm(ifb[455]);
    for (int i = 0; i < 32; i++){
      int n = i*256 + t;
      float p = p_[i] * invS;
      dstww[n] = wg * (ag * allocv[n] + (1.0f - ag) * p);
    }
  }
}

// ---------------- K4: batch-mean write weight w[n], wsum, fg_mean, e[], v[] ----------------
__global__ __launch_bounds__(256) void k_wmean(float* __restrict__ ws)
{
  int t = threadIdx.x, n = blockIdx.x*256 + t;
  const float* ww = ws + OFF_WW;
  float s = 0.0f;
  #pragma unroll 8
  for (int b = 0; b < 32; b++) s += ww[(size_t)b*NN + n];
  float w_n = s * (1.0f/32.0f);
  ws[OFF_WV + n] = w_n;
  __shared__ float red[256];
  red[t] = w_n; __syncthreads();
  for (int s2 = 128; s2 > 0; s2 >>= 1){ if (t < s2) red[t] += red[t+s2]; __syncthreads(); }
  if (t == 0) atomicAdd(ws + OFF_SCAL, red[0]);
  if (blockIdx.x == 0){
    __syncthreads();
    const float* iface = ws + OFF_IFACE;
    red[t] = (t < 32) ? sigm(iface[t*ISZ + 453]) : 0.0f;
    __syncthreads();
    for (int s2 = 128; s2 > 0; s2 >>= 1){ if (t < s2) red[t] += red[t+s2]; __syncthreads(); }
    if (t == 0) ws[OFF_SCAL + 1] = red[0] * (1.0f/32.0f);
    if (t < 64){
      float se = 0.0f, sv = 0.0f;
      for (int b = 0; b < 32; b++){
        se += sigm(iface[b*ISZ + 389 + t]);
        sv += iface[b*ISZ + 325 + t];
      }
      ws[OFF_E + t] = se * (1.0f/32.0f);
      ws[OFF_V + t] = sv * (1.0f/32.0f);
    }
  }
}

// ---------------- K5: MFMA link GEMMs.
// BWD=true : bwd[bh,i] = sum_k rcw[bh,k]*link[i,k]   (+ fused new_link write)
// BWD=false: fwd[bh,m] = sum_n rcw[bh,n]*link[n,m]
// Epilogue: rw[bh, col] += mode[bh] * acc   (atomic; 4-way ksplit contention)
template<bool BWD>
__global__ __launch_bounds__(256) void k_link_mfma(
    const float* __restrict__ link, const float* __restrict__ prec,
    float* __restrict__ ws, float* __restrict__ new_link)
{
  const __bf16* rcwb = (const __bf16*)(ws + OFF_RCWB);
  const float* modes = ws + OFF_MODE + (BWD ? 0 : 128);
  const float* wv = ws + OFF_WV;
  float* rw = ws + OFF_RW;
  int t = threadIdx.x;
  int w = t >> 6, lane = t & 63;
  int c = lane & 31, g = lane >> 5;
  int col = blockIdx.x*128 + w*32 + c;          // output column (bwd: i, fwd: m)
  int k0 = blockIdx.y * 2048, k1 = k0 + 2048;
  f32x16 acc[4] = {};
  float w_n = 0.0f;
  if (BWD) w_n = wv[col];
  #pragma unroll 2
  for (int kt = k0; kt < k1; kt += 16){
    int kb = kt + 8*g;
    float f[8];
    if (BWD){
      const float4* Lp = (const float4*)(link + (size_t)col*NN + kb);
      float4 L0 = Lp[0], L1 = Lp[1];
      f[0]=L0.x; f[1]=L0.y; f[2]=L0.z; f[3]=L0.w;
      f[4]=L1.x; f[5]=L1.y; f[6]=L1.z; f[7]=L1.w;
      // fused new_link = (1 - w_i - w_k)*L + w_i*prec[k], diag 0
      const float4* pp  = (const float4*)(prec + kb);
      const float4* wmp = (const float4*)(wv + kb);
      float4 p0 = pp[0], p1 = pp[1], q0 = wmp[0], q1 = wmp[1];
      float4 o0, o1;
      o0.x = (col==kb+0)?0.0f:((1.0f - w_n - q0.x)*L0.x + w_n*p0.x);
      o0.y = (col==kb+1)?0.0f:((1.0f - w_n - q0.y)*L0.y + w_n*p0.y);
      o0.z = (col==kb+2)?0.0f:((1.0f - w_n - q0.z)*L0.z + w_n*p0.z);
      o0.w = (col==kb+3)?0.0f:((1.0f - w_n - q0.w)*L0.w + w_n*p0.w);
      o1.x = (col==kb+4)?0.0f:((1.0f - w_n - q1.x)*L1.x + w_n*p1.x);
      o1.y = (col==kb+5)?0.0f:((1.0f - w_n - q1.y)*L1.y + w_n*p1.y);
      o1.z = (col==kb+6)?0.0f:((1.0f - w_n - q1.z)*L1.z + w_n*p1.z);
      o1.w = (col==kb+7)?0.0f:((1.0f - w_n - q1.w)*L1.w + w_n*p1.w);
      float4* dst = (float4*)(new_link + (size_t)col*NN + kb);
      dst[0] = o0; dst[1] = o1;
    } else {
      #pragma unroll
      for (int j = 0; j < 8; j++) f[j] = link[(size_t)(kb + j)*NN + col];
    }
    bf16x8 bfr;
    #pragma unroll
    for (int j = 0; j < 8; j++) bfr[j] = (__bf16)f[j];
    #pragma unroll
    for (int mt = 0; mt < 4; mt++){
      bf16x8 af = *(const bf16x8*)(rcwb + (size_t)(mt*32 + c)*NN + kb);
      acc[mt] = __builtin_amdgcn_mfma_f32_32x32x16_bf16(af, bfr, acc[mt], 0, 0, 0);
    }
  }
  #pragma unroll
  for (int mt = 0; mt < 4; mt++){
    #pragma unroll
    for (int r = 0; r < 16; r++){
      int row = mt*32 + (r & 3) + 8*(r >> 2) + 4*g;
      atomicAdd(&rw[(size_t)row*NN + col], modes[row] * acc[mt][r]);
    }
  }
}

// ---------------- K6: read vectors (rv = rw @ memory), atomic into zeroed out ----------------
__global__ __launch_bounds__(256) void k_read_vectors(
    const float* __restrict__ memory, const float* __restrict__ ws_c, float* __restrict__ out)
{
  int bh = blockIdx.x, p = blockIdx.y, t = threadIdx.x;
  int sub = t >> 6, j = t & 63;
  int n0 = p*1024 + sub*256;
  const float* rwp = ws_c + OFF_RW + (size_t)bh*NN + n0;
  const float* mp  = memory + (size_t)n0*64 + j;
  float a0=0, a1=0, a2=0, a3=0;
  for (int i = 0; i < 256; i += 4){
    a0 += rwp[i+0]*mp[(i+0)*64];
    a1 += rwp[i+1]*mp[(i+1)*64];
    a2 += rwp[i+2]*mp[(i+2)*64];
    a3 += rwp[i+3]*mp[(i+3)*64];
  }
  __shared__ float red[4][64];
  red[sub][j] = ((a0+a1)+(a2+a3));
  __syncthreads();
  if (t < 64){
    float s = red[0][t] + red[1][t] + red[2][t] + red[3][t];
    atomicAdd(&out[OUT_RV + (bh>>2)*256 + (bh&3)*64 + t], s);
  }
}

// ---------------- K7: usage + precedence ----------------
__global__ __launch_bounds__(256) void k_usage_prec(
    const float* __restrict__ usage, const float* __restrict__ prec,
    const float* __restrict__ ws_c, float* __restrict__ out)
{
  int b = blockIdx.x, t = threadIdx.x;
  int rg = t >> 5, c = t & 31;
  int n = b*32 + c;
  const float* rw = ws_c + OFF_RW;
  float s = 0.0f;
  #pragma unroll
  for (int r = 0; r < 16; r++) s += rw[(size_t)(rg*16 + r)*NN + n];
  __shared__ float red[8][32];
  red[rg][c] = s;
  __syncthreads();
  if (t < 32){
    float sum = red[0][t]+red[1][t]+red[2][t]+red[3][t]+red[4][t]+red[5][t]+red[6][t]+red[7][t];
    float fg = ws_c[OFF_SCAL + 1];
    float retention = 1.0f - fg * (sum * (1.0f/128.0f));
    int nn = b*32 + t;
    float u = usage[nn], w_n = ws_c[OFF_WV + nn];
    out[OUT_USAGE + nn] = (u + w_n - u*w_n) * retention;
    out[OUT_PREC + nn] = (1.0f - ws_c[OFF_SCAL]) * prec[nn] + w_n;
  }
}

// ---------------- K8: memory update ----------------
__global__ __launch_bounds__(256) void k_new_memory(
    const float* __restrict__ memory, const float* __restrict__ ws_c, float* __restrict__ out)
{
  int idx = blockIdx.x*256 + threadIdx.x;
  int n = idx >> 6, j = idx & 63;
  float w_n = ws_c[OFF_WV + n];
  out[OUT_MEM + idx] = memory[idx] * (1.0f - w_n * ws_c[OFF_E + j]) + w_n * ws_c[OFF_V + j];
}

extern "C" void kernel_launch(void* const* d_in, const int* in_sizes, int n_in,
                              void* d_out, int out_size, void* d_ws, size_t ws_size,
                              hipStream_t stream)
{
  const float* input_data = (const float*)d_in[0];
  const float* prev_reads = (const float*)d_in[1];
  const float* h0         = (const float*)d_in[2];
  const float* c0         = (const float*)d_in[3];
  const float* memory     = (const float*)d_in[4];
  const float* usage      = (const float*)d_in[5];
  const float* link       = (const float*)d_in[6];
  const float* prec       = (const float*)d_in[7];
  const float* W_ih       = (const float*)d_in[8];
  const float* W_hh       = (const float*)d_in[9];
  const float* b_ih       = (const float*)d_in[10];
  const float* b_hh       = (const float*)d_in[11];
  const float* W_if       = (const float*)d_in[12];
  const float* b_if       = (const float*)d_in[13];
  float* out = (float*)d_out;
  float* ws  = (float*)d_ws;

  hipMemsetAsync(ws + OFF_SCAL, 0, 2*sizeof(float), stream);

  k_controller<<<32, 256, 0, stream>>>(input_data, prev_reads, h0, c0,
                                       W_ih, W_hh, b_ih, b_hh, W_if, b_if, out, ws);
  k_alloc<<<1, 1024, 0, stream>>>(usage, ws);
  k_content<<<dim3(32,5), 256, 0, stream>>>(memory, ws);
  k_wmean<<<32, 256, 0, stream>>>(ws);
  k_link_mfma<true ><<<dim3(64,4), 256, 0, stream>>>(link, prec, ws, out + OUT_LINK);
  k_link_mfma<false><<<dim3(64,4), 256, 0, stream>>>(link, prec, ws, out + OUT_LINK);
  k_read_vectors<<<dim3(128,8), 256, 0, stream>>>(memory, ws, out);
  k_usage_prec<<<256, 256, 0, stream>>>(usage, prec, ws, out);
  k_new_memory<<<2048, 256, 0, stream>>>(memory, ws, out);
}